// Round 1
// baseline (912.427 us; speedup 1.0000x reference)
//
#include <hip/hip_runtime.h>

#define LEAKY_SLOPE 0.01f
#define NUM_GRAPHS 512

// ---------------------------------------------------------------------------
// Edge scatter: agg[dst] += x[src] * w   (one 64-lane wave per edge, lane = feature)
// ---------------------------------------------------------------------------
__global__ __launch_bounds__(256)
void scatter_kernel(const float* __restrict__ xin, const int* __restrict__ src,
                    const int* __restrict__ dst, const float* __restrict__ w,
                    float* __restrict__ agg, int E) {
    const int e = blockIdx.x * 4 + (threadIdx.x >> 6);
    if (e >= E) return;
    const int lane = threadIdx.x & 63;
    const int s = src[e];
    const int d = dst[e];
    const float wt = w[e];
    const float v = xin[s * 64 + lane] * wt;
    atomicAdd(&agg[d * 64 + lane], v);
}

// ---------------------------------------------------------------------------
// Node transform: out = leaky(agg @ Wrel + xin @ Wroot + b)
// One wave per row (grid-stride). Thread `lane` owns output column `lane`:
// it holds Wrel[:,lane] and Wroot[:,lane] in 128 VGPRs; row elements are
// broadcast with v_readlane (VALU pipe) — no LDS in the inner loop.
// If FUSE_POOL: instead of storing the row, atomically accumulate it into
// pooled[batch[row]] and bump cnt[batch[row]].
// ---------------------------------------------------------------------------
template <bool FUSE_POOL>
__global__ __launch_bounds__(256)
void transform_kernel(const float* __restrict__ agg, const float* __restrict__ xin,
                      const float* __restrict__ Wrel, const float* __restrict__ Wroot,
                      const float* __restrict__ bias, float* __restrict__ xout,
                      const int* __restrict__ batch, float* __restrict__ pooled,
                      float* __restrict__ cnt, int N) {
    const int lane = threadIdx.x & 63;
    const int gwave = blockIdx.x * (blockDim.x >> 6) + (threadIdx.x >> 6);
    const int nwaves = gridDim.x * (blockDim.x >> 6);

    float wrel[64], wroot[64];
#pragma unroll
    for (int k = 0; k < 64; ++k) {
        wrel[k]  = Wrel[k * 64 + lane];
        wroot[k] = Wroot[k * 64 + lane];
    }
    const float b = bias[lane];

    for (int row = gwave; row < N; row += nwaves) {
        const float av = agg[row * 64 + lane];
        const float xv = xin[row * 64 + lane];
        float acc = b;
#pragma unroll
        for (int k = 0; k < 64; ++k) {
            const float a_k = __int_as_float(__builtin_amdgcn_readlane(__float_as_int(av), k));
            const float x_k = __int_as_float(__builtin_amdgcn_readlane(__float_as_int(xv), k));
            acc += a_k * wrel[k] + x_k * wroot[k];
        }
        acc = (acc > 0.0f) ? acc : LEAKY_SLOPE * acc;
        if (FUSE_POOL) {
            const int g = batch[row];
            atomicAdd(&pooled[g * 64 + lane], acc);
            if (lane == 0) atomicAdd(&cnt[g], 1.0f);
        } else {
            xout[row * 64 + lane] = acc;
        }
    }
}

// ---------------------------------------------------------------------------
// Final: out[g,:] = (pooled[g,:]/max(cnt,1)) @ Wl[64,8] + bl
// ---------------------------------------------------------------------------
__global__ __launch_bounds__(64)
void final_kernel(const float* __restrict__ pooled, const float* __restrict__ cnt,
                  const float* __restrict__ Wl, const float* __restrict__ bl,
                  float* __restrict__ out) {
    const int g = blockIdx.x;
    const int j = threadIdx.x;
    __shared__ float sp[64];
    const float c = fmaxf(cnt[g], 1.0f);
    sp[j] = pooled[g * 64 + j] / c;
    __syncthreads();
    if (j < 8) {
        float acc = bl[j];
#pragma unroll
        for (int k = 0; k < 64; ++k) acc += sp[k] * Wl[k * 8 + j];
        out[g * 8 + j] = acc;
    }
}

extern "C" void kernel_launch(void* const* d_in, const int* in_sizes, int n_in,
                              void* d_out, int out_size, void* d_ws, size_t ws_size,
                              hipStream_t stream) {
    const float* x      = (const float*)d_in[0];
    const int*   ei     = (const int*)  d_in[1];  // [2,E]: src then dst
    const float* w      = (const float*)d_in[2];
    const int*   batch  = (const int*)  d_in[3];
    const float* W1root = (const float*)d_in[4];
    const float* W1rel  = (const float*)d_in[5];
    const float* b1     = (const float*)d_in[6];
    const float* W2root = (const float*)d_in[7];
    const float* W2rel  = (const float*)d_in[8];
    const float* b2     = (const float*)d_in[9];
    const float* Wl     = (const float*)d_in[10];
    const float* bl     = (const float*)d_in[11];
    float* out = (float*)d_out;

    const int E = in_sizes[2];      // 1,250,000
    const int N = in_sizes[3];      // 100,000
    const int* src = ei;
    const int* dst = ei + E;

    float* bufA   = (float*)d_ws;          // [N*64] aggregation buffer
    float* bufB   = bufA + (size_t)N * 64; // [N*64] x1
    float* pooled = bufB + (size_t)N * 64; // [512*64]
    float* cnt    = pooled + NUM_GRAPHS * 64; // [512]

    const size_t nodeBytes = (size_t)N * 64 * sizeof(float);

    // Layer 1
    hipMemsetAsync(bufA, 0, nodeBytes, stream);
    hipMemsetAsync(pooled, 0, (NUM_GRAPHS * 64 + NUM_GRAPHS) * sizeof(float), stream);
    scatter_kernel<<<(E + 3) / 4, 256, 0, stream>>>(x, src, dst, w, bufA, E);
    transform_kernel<false><<<1024, 256, 0, stream>>>(bufA, x, W1rel, W1root, b1,
                                                      bufB, nullptr, nullptr, nullptr, N);
    // Layer 2
    hipMemsetAsync(bufA, 0, nodeBytes, stream);
    scatter_kernel<<<(E + 3) / 4, 256, 0, stream>>>(bufB, src, dst, w, bufA, E);
    transform_kernel<true><<<1024, 256, 0, stream>>>(bufA, bufB, W2rel, W2root, b2,
                                                     nullptr, batch, pooled, cnt, N);
    // Pool + classify
    final_kernel<<<NUM_GRAPHS, 64, 0, stream>>>(pooled, cnt, Wl, bl, out);
}

// Round 2
// 632.400 us; speedup vs baseline: 1.4428x; 1.4428x over previous
//
#include <hip/hip_runtime.h>

#define LEAKY_SLOPE 0.01f
#define NUM_GRAPHS 512
#define SCAN_TILE 1024

// ---------------------------------------------------------------------------
// CSR build step 1: degree histogram (int atomics on 400 KB L2-resident array)
// ---------------------------------------------------------------------------
__global__ __launch_bounds__(256)
void hist_kernel(const int* __restrict__ dst, int* __restrict__ deg, int E) {
    int e = blockIdx.x * blockDim.x + threadIdx.x;
    if (e < E) atomicAdd(&deg[dst[e]], 1);
}

// ---------------------------------------------------------------------------
// CSR build step 2: per-block exclusive scan (in-place deg -> excl), 1024/block
// ---------------------------------------------------------------------------
__global__ __launch_bounds__(SCAN_TILE)
void scan1_kernel(int* __restrict__ deg, int* __restrict__ blockSums, int N) {
    __shared__ int buf[2][SCAN_TILE];
    const int i = blockIdx.x * SCAN_TILE + threadIdx.x;
    const int v = (i < N) ? deg[i] : 0;
    int pp = 0;
    buf[0][threadIdx.x] = v;
    __syncthreads();
    for (int off = 1; off < SCAN_TILE; off <<= 1) {
        int val = buf[pp][threadIdx.x];
        if ((int)threadIdx.x >= off) val += buf[pp][threadIdx.x - off];
        buf[pp ^ 1][threadIdx.x] = val;
        pp ^= 1;
        __syncthreads();
    }
    const int inc = buf[pp][threadIdx.x];
    if (i < N) deg[i] = inc - v;  // exclusive scan, in place
    if (threadIdx.x == SCAN_TILE - 1) blockSums[blockIdx.x] = inc;
}

// ---------------------------------------------------------------------------
// CSR build step 3: serial exclusive scan of the (<=128) block sums
// ---------------------------------------------------------------------------
__global__ void scan2_kernel(int* __restrict__ blockSums, int B) {
    if (threadIdx.x == 0 && blockIdx.x == 0) {
        int run = 0;
        for (int b = 0; b < B; ++b) { int t = blockSums[b]; blockSums[b] = run; run += t; }
    }
}

// ---------------------------------------------------------------------------
// CSR build step 4: add block offsets -> rowStart; init cursor
// ---------------------------------------------------------------------------
__global__ __launch_bounds__(256)
void scan3_kernel(const int* __restrict__ excl, const int* __restrict__ blockSums,
                  int* __restrict__ rowStart, int* __restrict__ cursor, int N, int E) {
    int i = blockIdx.x * blockDim.x + threadIdx.x;
    if (i < N) {
        int start = excl[i] + blockSums[i >> 10];
        rowStart[i] = start;
        cursor[i] = start;
    }
    if (i == 0) rowStart[N] = E;
}

// ---------------------------------------------------------------------------
// CSR build step 5: fill edge data (src, weight) packed to 8 B, dst-sorted
// ---------------------------------------------------------------------------
__global__ __launch_bounds__(256)
void fill_kernel(const int* __restrict__ src, const int* __restrict__ dst,
                 const float* __restrict__ w, int* __restrict__ cursor,
                 int2* __restrict__ edata, int E) {
    int e = blockIdx.x * blockDim.x + threadIdx.x;
    if (e < E) {
        int pos = atomicAdd(&cursor[dst[e]], 1);
        edata[pos] = make_int2(src[e], __float_as_int(w[e]));
    }
}

// ---------------------------------------------------------------------------
// Gather aggregation: one wave per node, lane = feature. Register accumulate,
// single coalesced 256 B store. No atomics.
// ---------------------------------------------------------------------------
__global__ __launch_bounds__(256)
void gather_kernel(const float* __restrict__ xin, const int* __restrict__ rowStart,
                   const int2* __restrict__ edata, float* __restrict__ agg, int N) {
    const int node = blockIdx.x * 4 + (threadIdx.x >> 6);
    if (node >= N) return;
    const int lane = threadIdx.x & 63;
    const int s = rowStart[node];
    const int e = rowStart[node + 1];
    float acc = 0.0f;
    int j = s;
    for (; j + 1 < e; j += 2) {  // 2-deep software pipeline for gather latency
        int2 e0 = edata[j];
        int2 e1 = edata[j + 1];
        float v0 = xin[(size_t)e0.x * 64 + lane];
        float v1 = xin[(size_t)e1.x * 64 + lane];
        acc += v0 * __int_as_float(e0.y);
        acc += v1 * __int_as_float(e1.y);
    }
    if (j < e) {
        int2 e0 = edata[j];
        acc += xin[(size_t)e0.x * 64 + lane] * __int_as_float(e0.y);
    }
    agg[(size_t)node * 64 + lane] = acc;
}

// ---------------------------------------------------------------------------
// Node transform: out = leaky(agg @ Wrel + xin @ Wroot + b)
// Wave per row; lane owns output column; weights in 128 VGPRs; row elements
// broadcast via readlane. Dual accumulators break the dependent FMA chain.
// ---------------------------------------------------------------------------
template <bool FUSE_POOL>
__global__ __launch_bounds__(256)
void transform_kernel(const float* __restrict__ agg, const float* __restrict__ xin,
                      const float* __restrict__ Wrel, const float* __restrict__ Wroot,
                      const float* __restrict__ bias, float* __restrict__ xout,
                      const int* __restrict__ batch, float* __restrict__ pooled,
                      float* __restrict__ cnt, int N) {
    const int lane = threadIdx.x & 63;
    const int gwave = blockIdx.x * (blockDim.x >> 6) + (threadIdx.x >> 6);
    const int nwaves = gridDim.x * (blockDim.x >> 6);

    float wrel[64], wroot[64];
#pragma unroll
    for (int k = 0; k < 64; ++k) {
        wrel[k]  = Wrel[k * 64 + lane];
        wroot[k] = Wroot[k * 64 + lane];
    }
    const float b = bias[lane];

    for (int row = gwave; row < N; row += nwaves) {
        const float av = agg[(size_t)row * 64 + lane];
        const float xv = xin[(size_t)row * 64 + lane];
        float acc0 = b, acc1 = 0.0f;
#pragma unroll
        for (int k = 0; k < 64; k += 2) {
            float a0 = __int_as_float(__builtin_amdgcn_readlane(__float_as_int(av), k));
            float x0 = __int_as_float(__builtin_amdgcn_readlane(__float_as_int(xv), k));
            float a1 = __int_as_float(__builtin_amdgcn_readlane(__float_as_int(av), k + 1));
            float x1 = __int_as_float(__builtin_amdgcn_readlane(__float_as_int(xv), k + 1));
            acc0 += a0 * wrel[k]     + x0 * wroot[k];
            acc1 += a1 * wrel[k + 1] + x1 * wroot[k + 1];
        }
        float acc = acc0 + acc1;
        acc = (acc > 0.0f) ? acc : LEAKY_SLOPE * acc;
        if (FUSE_POOL) {
            const int g = batch[row];
            atomicAdd(&pooled[g * 64 + lane], acc);
            if (lane == 0) atomicAdd(&cnt[g], 1.0f);
        } else {
            xout[(size_t)row * 64 + lane] = acc;
        }
    }
}

// ---------------------------------------------------------------------------
// Final: out[g,:] = (pooled[g,:]/max(cnt,1)) @ Wl[64,8] + bl
// ---------------------------------------------------------------------------
__global__ __launch_bounds__(64)
void final_kernel(const float* __restrict__ pooled, const float* __restrict__ cnt,
                  const float* __restrict__ Wl, const float* __restrict__ bl,
                  float* __restrict__ out) {
    const int g = blockIdx.x;
    const int j = threadIdx.x;
    __shared__ float sp[64];
    const float c = fmaxf(cnt[g], 1.0f);
    sp[j] = pooled[g * 64 + j] / c;
    __syncthreads();
    if (j < 8) {
        float acc = bl[j];
#pragma unroll
        for (int k = 0; k < 64; ++k) acc += sp[k] * Wl[k * 8 + j];
        out[g * 8 + j] = acc;
    }
}

extern "C" void kernel_launch(void* const* d_in, const int* in_sizes, int n_in,
                              void* d_out, int out_size, void* d_ws, size_t ws_size,
                              hipStream_t stream) {
    const float* x      = (const float*)d_in[0];
    const int*   ei     = (const int*)  d_in[1];  // [2,E]: src then dst
    const float* w      = (const float*)d_in[2];
    const int*   batch  = (const int*)  d_in[3];
    const float* W1root = (const float*)d_in[4];
    const float* W1rel  = (const float*)d_in[5];
    const float* b1     = (const float*)d_in[6];
    const float* W2root = (const float*)d_in[7];
    const float* W2rel  = (const float*)d_in[8];
    const float* b2     = (const float*)d_in[9];
    const float* Wl     = (const float*)d_in[10];
    const float* bl     = (const float*)d_in[11];
    float* out = (float*)d_out;

    const int E = in_sizes[2];      // 1,250,000
    const int N = in_sizes[3];      // 100,000
    const int* src = ei;
    const int* dst = ei + E;

    // Workspace layout (~62.4 MB)
    float* bufA     = (float*)d_ws;                    // [N*64] agg
    float* bufB     = bufA + (size_t)N * 64;           // [N*64] x1
    int2*  edata    = (int2*)(bufB + (size_t)N * 64);  // [E]
    int*   rowStart = (int*)(edata + E);               // [N+1]
    int*   cursor   = rowStart + (N + 1);              // [N]
    int*   deg      = cursor + N;                      // [N] (becomes excl-scan)
    int*   blockSums= deg + N;                         // [128]
    float* pooled   = (float*)(blockSums + 128);       // [512*64]
    float* cnt      = pooled + NUM_GRAPHS * 64;        // [512]

    const int edgeBlocks = (E + 255) / 256;
    const int scanBlocks = (N + SCAN_TILE - 1) / SCAN_TILE;   // 98

    // ---- CSR build (once, reused by both layers) ----
    hipMemsetAsync(deg, 0, (size_t)N * sizeof(int), stream);
    hipMemsetAsync(pooled, 0, (NUM_GRAPHS * 64 + NUM_GRAPHS) * sizeof(float), stream);
    hist_kernel<<<edgeBlocks, 256, 0, stream>>>(dst, deg, E);
    scan1_kernel<<<scanBlocks, SCAN_TILE, 0, stream>>>(deg, blockSums, N);
    scan2_kernel<<<1, 64, 0, stream>>>(blockSums, scanBlocks);
    scan3_kernel<<<(N + 255) / 256, 256, 0, stream>>>(deg, blockSums, rowStart, cursor, N, E);
    fill_kernel<<<edgeBlocks, 256, 0, stream>>>(src, dst, w, cursor, edata, E);

    // ---- Layer 1 ----
    gather_kernel<<<(N + 3) / 4, 256, 0, stream>>>(x, rowStart, edata, bufA, N);
    transform_kernel<false><<<1024, 256, 0, stream>>>(bufA, x, W1rel, W1root, b1,
                                                      bufB, nullptr, nullptr, nullptr, N);
    // ---- Layer 2 ----
    gather_kernel<<<(N + 3) / 4, 256, 0, stream>>>(bufB, rowStart, edata, bufA, N);
    transform_kernel<true><<<1024, 256, 0, stream>>>(bufA, bufB, W2rel, W2root, b2,
                                                     nullptr, batch, pooled, cnt, N);
    // ---- Pool + classify ----
    final_kernel<<<NUM_GRAPHS, 64, 0, stream>>>(pooled, cnt, Wl, bl, out);
}

// Round 3
// 568.268 us; speedup vs baseline: 1.6056x; 1.1129x over previous
//
#include <hip/hip_runtime.h>

#define LEAKY_SLOPE 0.01f
#define NUM_GRAPHS 512
#define SCAN_TILE 1024

typedef __attribute__((ext_vector_type(8))) short short8;   // 8 x bf16 (4 VGPRs)
typedef __attribute__((ext_vector_type(4))) float f32x4;    // MFMA C/D

// fp32 -> bf16 round-to-nearest-even
static __device__ __forceinline__ unsigned short f2bf(float f) {
    unsigned u = __float_as_uint(f);
    u += 0x7FFFu + ((u >> 16) & 1u);
    return (unsigned short)(u >> 16);
}
static __device__ __forceinline__ float bf2f(unsigned short h) {
    return __uint_as_float(((unsigned)h) << 16);
}

// ---------------------------------------------------------------------------
// CSR build: histogram -> scan -> fill (dst-sorted edge list, built once)
// ---------------------------------------------------------------------------
__global__ __launch_bounds__(256)
void hist_kernel(const int* __restrict__ dst, int* __restrict__ deg, int E) {
    int e = blockIdx.x * blockDim.x + threadIdx.x;
    if (e < E) atomicAdd(&deg[dst[e]], 1);
}

__global__ __launch_bounds__(SCAN_TILE)
void scan1_kernel(int* __restrict__ deg, int* __restrict__ blockSums, int N) {
    __shared__ int buf[2][SCAN_TILE];
    const int i = blockIdx.x * SCAN_TILE + threadIdx.x;
    const int v = (i < N) ? deg[i] : 0;
    int pp = 0;
    buf[0][threadIdx.x] = v;
    __syncthreads();
    for (int off = 1; off < SCAN_TILE; off <<= 1) {
        int val = buf[pp][threadIdx.x];
        if ((int)threadIdx.x >= off) val += buf[pp][threadIdx.x - off];
        buf[pp ^ 1][threadIdx.x] = val;
        pp ^= 1;
        __syncthreads();
    }
    const int inc = buf[pp][threadIdx.x];
    if (i < N) deg[i] = inc - v;  // exclusive, in place
    if (threadIdx.x == SCAN_TILE - 1) blockSums[blockIdx.x] = inc;
}

__global__ void scan2_kernel(int* __restrict__ blockSums, int B) {
    if (threadIdx.x == 0 && blockIdx.x == 0) {
        int run = 0;
        for (int b = 0; b < B; ++b) { int t = blockSums[b]; blockSums[b] = run; run += t; }
    }
}

__global__ __launch_bounds__(256)
void scan3_kernel(const int* __restrict__ excl, const int* __restrict__ blockSums,
                  int* __restrict__ rowStart, int* __restrict__ cursor, int N, int E) {
    int i = blockIdx.x * blockDim.x + threadIdx.x;
    if (i < N) {
        int start = excl[i] + blockSums[i >> 10];
        rowStart[i] = start;
        cursor[i] = start;
    }
    if (i == 0) rowStart[N] = E;
}

__global__ __launch_bounds__(256)
void fill_kernel(const int* __restrict__ src, const int* __restrict__ dst,
                 const float* __restrict__ w, int* __restrict__ cursor,
                 int2* __restrict__ edata, int E) {
    int e = blockIdx.x * blockDim.x + threadIdx.x;
    if (e < E) {
        int pos = atomicAdd(&cursor[dst[e]], 1);
        edata[pos] = make_int2(src[e], __float_as_int(w[e]));
    }
}

// ---------------------------------------------------------------------------
// Prep: x fp32 -> bf16
// ---------------------------------------------------------------------------
__global__ __launch_bounds__(256)
void prep_x_kernel(const float* __restrict__ x, unsigned short* __restrict__ xB, int n2) {
    int i = blockIdx.x * blockDim.x + threadIdx.x;   // one thread per 2 elements
    if (i < n2) {
        float2 f = ((const float2*)x)[i];
        ushort2 o = make_ushort2(f2bf(f.x), f2bf(f.y));
        ((ushort2*)xB)[i] = o;
    }
}

// Prep: Bt[n][k] bf16, k<64 -> Wrel[k][n], k>=64 -> Wroot[k-64][n]   (64x128)
__global__ __launch_bounds__(256)
void prep_B_kernel(const float* __restrict__ Wrel, const float* __restrict__ Wroot,
                   unsigned short* __restrict__ Bt) {
    int idx = blockIdx.x * blockDim.x + threadIdx.x;  // 64*128 = 8192
    if (idx < 64 * 128) {
        int n = idx >> 7, k = idx & 127;
        float v = (k < 64) ? Wrel[k * 64 + n] : Wroot[(k - 64) * 64 + n];
        Bt[idx] = f2bf(v);
    }
}

// Prep: per-graph node counts
__global__ __launch_bounds__(256)
void hist_batch_kernel(const int* __restrict__ batch, float* __restrict__ cnt, int N) {
    int i = blockIdx.x * blockDim.x + threadIdx.x;
    if (i < N) atomicAdd(&cnt[batch[i]], 1.0f);
}

// ---------------------------------------------------------------------------
// Gather aggregation (bf16 in / bf16 out, fp32 register accumulate)
// one wave per node, lane = feature
// ---------------------------------------------------------------------------
__global__ __launch_bounds__(256)
void gather_kernel(const unsigned short* __restrict__ xB, const int* __restrict__ rowStart,
                   const int2* __restrict__ edata, unsigned short* __restrict__ aggB, int N) {
    const int node = blockIdx.x * 4 + (threadIdx.x >> 6);
    if (node >= N) return;
    const int lane = threadIdx.x & 63;
    const int s = rowStart[node];
    const int e = rowStart[node + 1];
    float acc = 0.0f;
    int j = s;
    for (; j + 1 < e; j += 2) {
        int2 e0 = edata[j];
        int2 e1 = edata[j + 1];
        float v0 = bf2f(xB[(size_t)e0.x * 64 + lane]);
        float v1 = bf2f(xB[(size_t)e1.x * 64 + lane]);
        acc += v0 * __int_as_float(e0.y);
        acc += v1 * __int_as_float(e1.y);
    }
    if (j < e) {
        int2 e0 = edata[j];
        acc += bf2f(xB[(size_t)e0.x * 64 + lane]) * __int_as_float(e0.y);
    }
    aggB[(size_t)node * 64 + lane] = f2bf(acc);
}

// ---------------------------------------------------------------------------
// MFMA node transform: out = leaky([agg | root] @ Bt^T + b)
// A = [aggB | rootB] (bf16, k<64 agg, k>=64 root), Bt[n][k] 64x128 bf16.
// Block = 128 rows x 64 cols; wave = 32 rows (2 m-strips) x 4 n-tiles.
// A/B fragments loaded directly from global (no LDS). 16x16x32 bf16 MFMA.
// Layouts (HW-verified): A[m=lane&15][k=quad*8+j]; D col=lane&15, row=quad*4+reg.
// ---------------------------------------------------------------------------
template <bool POOL>
__global__ __launch_bounds__(256)
void mfma_transform(const unsigned short* __restrict__ aggB,
                    const unsigned short* __restrict__ rootB,
                    const unsigned short* __restrict__ Bt,
                    const float* __restrict__ bias,
                    unsigned short* __restrict__ xoutB,
                    const int* __restrict__ batch,
                    float* __restrict__ pooled, int N) {
    const int wave = threadIdx.x >> 6;
    const int lane = threadIdx.x & 63;
    const int quad = lane >> 4;
    const int l16  = lane & 15;
    const int m0   = blockIdx.x * 128 + wave * 32;

    // B fragments: 4 n-tiles x 4 k-steps (L1-resident, shared by all blocks)
    short8 bf[4][4];
#pragma unroll
    for (int t = 0; t < 4; ++t)
#pragma unroll
        for (int k = 0; k < 4; ++k)
            bf[t][k] = *(const short8*)(Bt + (t * 16 + l16) * 128 + k * 32 + quad * 8);

    f32x4 acc[2][4];
#pragma unroll
    for (int s = 0; s < 2; ++s)
#pragma unroll
        for (int t = 0; t < 4; ++t)
            acc[s][t] = (f32x4){0.f, 0.f, 0.f, 0.f};

#pragma unroll
    for (int s = 0; s < 2; ++s) {
        int row = m0 + s * 16 + l16;
        int rowc = row < N ? row : N - 1;   // clamp; garbage rows masked at store
        const unsigned short* arow = aggB  + (size_t)rowc * 64;
        const unsigned short* xrow = rootB + (size_t)rowc * 64;
        short8 af[4];
        af[0] = *(const short8*)(arow + quad * 8);
        af[1] = *(const short8*)(arow + 32 + quad * 8);
        af[2] = *(const short8*)(xrow + quad * 8);
        af[3] = *(const short8*)(xrow + 32 + quad * 8);
#pragma unroll
        for (int t = 0; t < 4; ++t)
#pragma unroll
            for (int k = 0; k < 4; ++k)
                acc[s][t] = __builtin_amdgcn_mfma_f32_16x16x32_bf16(af[k], bf[t][k],
                                                                    acc[s][t], 0, 0, 0);
    }

    // Epilogue
#pragma unroll
    for (int s = 0; s < 2; ++s) {
#pragma unroll
        for (int t = 0; t < 4; ++t) {
            const int col = t * 16 + l16;
            const float b = bias[col];
            const int rowbase = m0 + s * 16 + quad * 4;
            if (!POOL) {
#pragma unroll
                for (int r = 0; r < 4; ++r) {
                    int row = rowbase + r;
                    if (row < N) {
                        float v = acc[s][t][r] + b;
                        v = (v > 0.0f) ? v : LEAKY_SLOPE * v;
                        xoutB[(size_t)row * 64 + col] = f2bf(v);
                    }
                }
            } else {
                float v[4]; int g[4]; int nv = 0;
#pragma unroll
                for (int r = 0; r < 4; ++r) {
                    int row = rowbase + r;
                    if (row < N) {
                        float a = acc[s][t][r] + b;
                        a = (a > 0.0f) ? a : LEAKY_SLOPE * a;
                        v[nv] = a;
                        g[nv] = batch[row];
                        ++nv;
                    }
                }
                if (nv == 4 && g[0] == g[3]) {
                    atomicAdd(&pooled[g[0] * 64 + col], v[0] + v[1] + v[2] + v[3]);
                } else {
                    for (int r = 0; r < nv; ++r)
                        atomicAdd(&pooled[g[r] * 64 + col], v[r]);
                }
            }
        }
    }
}

// ---------------------------------------------------------------------------
// Final: out[g,:] = (pooled[g,:]/max(cnt,1)) @ Wl[64,8] + bl
// ---------------------------------------------------------------------------
__global__ __launch_bounds__(64)
void final_kernel(const float* __restrict__ pooled, const float* __restrict__ cnt,
                  const float* __restrict__ Wl, const float* __restrict__ bl,
                  float* __restrict__ out) {
    const int g = blockIdx.x;
    const int j = threadIdx.x;
    __shared__ float sp[64];
    const float c = fmaxf(cnt[g], 1.0f);
    sp[j] = pooled[g * 64 + j] / c;
    __syncthreads();
    if (j < 8) {
        float acc = bl[j];
#pragma unroll
        for (int k = 0; k < 64; ++k) acc += sp[k] * Wl[k * 8 + j];
        out[g * 8 + j] = acc;
    }
}

extern "C" void kernel_launch(void* const* d_in, const int* in_sizes, int n_in,
                              void* d_out, int out_size, void* d_ws, size_t ws_size,
                              hipStream_t stream) {
    const float* x      = (const float*)d_in[0];
    const int*   ei     = (const int*)  d_in[1];  // [2,E]: src then dst
    const float* w      = (const float*)d_in[2];
    const int*   batch  = (const int*)  d_in[3];
    const float* W1root = (const float*)d_in[4];
    const float* W1rel  = (const float*)d_in[5];
    const float* b1     = (const float*)d_in[6];
    const float* W2root = (const float*)d_in[7];
    const float* W2rel  = (const float*)d_in[8];
    const float* b2     = (const float*)d_in[9];
    const float* Wl     = (const float*)d_in[10];
    const float* bl     = (const float*)d_in[11];
    float* out = (float*)d_out;

    const int E = in_sizes[2];      // 1,250,000
    const int N = in_sizes[3];      // 100,000
    const int* src = ei;
    const int* dst = ei + E;

    // Workspace layout (16B-aligned chunks first)
    unsigned short* xB   = (unsigned short*)d_ws;          // [N*64] bf16
    unsigned short* aggB = xB   + (size_t)N * 64;          // [N*64]
    unsigned short* x1B  = aggB + (size_t)N * 64;          // [N*64]
    int2*  edata    = (int2*)(x1B + (size_t)N * 64);       // [E]
    unsigned short* Bt1 = (unsigned short*)(edata + E);    // [64*128]
    unsigned short* Bt2 = Bt1 + 64 * 128;                  // [64*128]
    int*   rowStart = (int*)(Bt2 + 64 * 128);              // [N+1]
    int*   cursor   = rowStart + (N + 1);                  // [N]
    int*   deg      = cursor + N;                          // [N]
    int*   blockSums= deg + N;                             // [128]
    float* pooled   = (float*)(blockSums + 128);           // [512*64]
    float* cnt      = pooled + NUM_GRAPHS * 64;            // [512]

    const int edgeBlocks = (E + 255) / 256;
    const int scanBlocks = (N + SCAN_TILE - 1) / SCAN_TILE;

    // ---- CSR build + prep ----
    hipMemsetAsync(deg, 0, (size_t)N * sizeof(int), stream);
    hipMemsetAsync(pooled, 0, (NUM_GRAPHS * 64 + NUM_GRAPHS) * sizeof(float), stream);
    hist_kernel<<<edgeBlocks, 256, 0, stream>>>(dst, deg, E);
    prep_x_kernel<<<(N * 32 + 255) / 256, 256, 0, stream>>>(x, xB, N * 32);
    prep_B_kernel<<<32, 256, 0, stream>>>(W1rel, W1root, Bt1);
    prep_B_kernel<<<32, 256, 0, stream>>>(W2rel, W2root, Bt2);
    hist_batch_kernel<<<(N + 255) / 256, 256, 0, stream>>>(batch, cnt, N);
    scan1_kernel<<<scanBlocks, SCAN_TILE, 0, stream>>>(deg, blockSums, N);
    scan2_kernel<<<1, 64, 0, stream>>>(blockSums, scanBlocks);
    scan3_kernel<<<(N + 255) / 256, 256, 0, stream>>>(deg, blockSums, rowStart, cursor, N, E);
    fill_kernel<<<edgeBlocks, 256, 0, stream>>>(src, dst, w, cursor, edata, E);

    const int tBlocks = (N + 127) / 128;
    // ---- Layer 1 ----
    gather_kernel<<<(N + 3) / 4, 256, 0, stream>>>(xB, rowStart, edata, aggB, N);
    mfma_transform<false><<<tBlocks, 256, 0, stream>>>(aggB, xB, Bt1, b1, x1B,
                                                       nullptr, nullptr, N);
    // ---- Layer 2 ----
    gather_kernel<<<(N + 3) / 4, 256, 0, stream>>>(x1B, rowStart, edata, aggB, N);
    mfma_transform<true><<<tBlocks, 256, 0, stream>>>(aggB, x1B, Bt2, b2, nullptr,
                                                      batch, pooled, N);
    // ---- Pool + classify ----
    final_kernel<<<NUM_GRAPHS, 64, 0, stream>>>(pooled, cnt, Wl, bl, out);
}

// Round 4
// 438.338 us; speedup vs baseline: 2.0816x; 1.2964x over previous
//
#include <hip/hip_runtime.h>

#define LEAKY_SLOPE 0.01f
#define NUM_GRAPHS 512
#define SCAN_TILE 1024

typedef __attribute__((ext_vector_type(8))) short short8;   // 8 x bf16 (4 VGPRs)
typedef __attribute__((ext_vector_type(4))) float f32x4;    // MFMA C/D

// fp32 -> bf16 round-to-nearest-even
static __device__ __forceinline__ unsigned short f2bf(float f) {
    unsigned u = __float_as_uint(f);
    u += 0x7FFFu + ((u >> 16) & 1u);
    return (unsigned short)(u >> 16);
}
static __device__ __forceinline__ float bf2f(unsigned short h) {
    return __uint_as_float(((unsigned)h) << 16);
}

// ---------------------------------------------------------------------------
// CSR build: histogram -> scan -> fill (dst-sorted edge list, built once/call)
// ---------------------------------------------------------------------------
__global__ __launch_bounds__(256)
void hist_kernel(const int* __restrict__ dst, int* __restrict__ deg, int E) {
    int e = blockIdx.x * blockDim.x + threadIdx.x;
    if (e < E) atomicAdd(&deg[dst[e]], 1);
}

__global__ __launch_bounds__(SCAN_TILE)
void scan1_kernel(int* __restrict__ deg, int* __restrict__ blockSums, int N) {
    __shared__ int buf[2][SCAN_TILE];
    const int i = blockIdx.x * SCAN_TILE + threadIdx.x;
    const int v = (i < N) ? deg[i] : 0;
    int pp = 0;
    buf[0][threadIdx.x] = v;
    __syncthreads();
    for (int off = 1; off < SCAN_TILE; off <<= 1) {
        int val = buf[pp][threadIdx.x];
        if ((int)threadIdx.x >= off) val += buf[pp][threadIdx.x - off];
        buf[pp ^ 1][threadIdx.x] = val;
        pp ^= 1;
        __syncthreads();
    }
    const int inc = buf[pp][threadIdx.x];
    if (i < N) deg[i] = inc - v;  // exclusive, in place
    if (threadIdx.x == SCAN_TILE - 1) blockSums[blockIdx.x] = inc;
}

__global__ void scan2_kernel(int* __restrict__ blockSums, int B) {
    if (threadIdx.x == 0 && blockIdx.x == 0) {
        int run = 0;
        for (int b = 0; b < B; ++b) { int t = blockSums[b]; blockSums[b] = run; run += t; }
    }
}

__global__ __launch_bounds__(256)
void scan3_kernel(const int* __restrict__ excl, const int* __restrict__ blockSums,
                  int* __restrict__ rowStart, int* __restrict__ cursor, int N, int E) {
    int i = blockIdx.x * blockDim.x + threadIdx.x;
    if (i < N) {
        int start = excl[i] + blockSums[i >> 10];
        rowStart[i] = start;
        cursor[i] = start;
    }
    if (i == 0) rowStart[N] = E;
}

__global__ __launch_bounds__(256)
void fill_kernel(const int* __restrict__ src, const int* __restrict__ dst,
                 const float* __restrict__ w, int* __restrict__ cursor,
                 int2* __restrict__ edata, int E) {
    int e = blockIdx.x * blockDim.x + threadIdx.x;
    if (e < E) {
        int pos = atomicAdd(&cursor[dst[e]], 1);
        edata[pos] = make_int2(src[e], __float_as_int(w[e]));
    }
}

// ---------------------------------------------------------------------------
// Prep: x fp32 -> bf16
// ---------------------------------------------------------------------------
__global__ __launch_bounds__(256)
void prep_x_kernel(const float* __restrict__ x, unsigned short* __restrict__ xB, int n2) {
    int i = blockIdx.x * blockDim.x + threadIdx.x;   // one thread per 2 elements
    if (i < n2) {
        float2 f = ((const float2*)x)[i];
        ushort2 o = make_ushort2(f2bf(f.x), f2bf(f.y));
        ((ushort2*)xB)[i] = o;
    }
}

// Prep both layers' Bt[n][k] (64x128 bf16 each): k<64 -> Wrel[k][n], else Wroot
__global__ __launch_bounds__(256)
void prep_B_kernel(const float* __restrict__ W1rel, const float* __restrict__ W1root,
                   const float* __restrict__ W2rel, const float* __restrict__ W2root,
                   unsigned short* __restrict__ Bt1, unsigned short* __restrict__ Bt2) {
    int idx = blockIdx.x * blockDim.x + threadIdx.x;  // 2 * 64*128 = 16384
    if (idx < 2 * 64 * 128) {
        int which = idx >> 13;
        int j = idx & 8191;
        int n = j >> 7, k = j & 127;
        const float* Wr = which ? W2rel : W1rel;
        const float* Wo = which ? W2root : W1root;
        float v = (k < 64) ? Wr[k * 64 + n] : Wo[(k - 64) * 64 + n];
        (which ? Bt2 : Bt1)[j] = f2bf(v);
    }
}

// ---------------------------------------------------------------------------
// Gather aggregation (bf16 in / bf16 out, fp32 register accumulate)
// one wave per node, lane = feature; 4-deep unroll, 2 independent accumulators
// ---------------------------------------------------------------------------
__global__ __launch_bounds__(256)
void gather_kernel(const unsigned short* __restrict__ xB, const int* __restrict__ rowStart,
                   const int2* __restrict__ edata, unsigned short* __restrict__ aggB, int N) {
    const int node = blockIdx.x * 4 + (threadIdx.x >> 6);
    if (node >= N) return;
    const int lane = threadIdx.x & 63;
    const int s = rowStart[node];
    const int e = rowStart[node + 1];
    float acc0 = 0.0f, acc1 = 0.0f;
    int j = s;
    for (; j + 3 < e; j += 4) {
        int2 e0 = edata[j];
        int2 e1 = edata[j + 1];
        int2 e2 = edata[j + 2];
        int2 e3 = edata[j + 3];
        float v0 = bf2f(xB[(size_t)e0.x * 64 + lane]);
        float v1 = bf2f(xB[(size_t)e1.x * 64 + lane]);
        float v2 = bf2f(xB[(size_t)e2.x * 64 + lane]);
        float v3 = bf2f(xB[(size_t)e3.x * 64 + lane]);
        acc0 += v0 * __int_as_float(e0.y);
        acc1 += v1 * __int_as_float(e1.y);
        acc0 += v2 * __int_as_float(e2.y);
        acc1 += v3 * __int_as_float(e3.y);
    }
    for (; j < e; ++j) {
        int2 e0 = edata[j];
        acc0 += bf2f(xB[(size_t)e0.x * 64 + lane]) * __int_as_float(e0.y);
    }
    aggB[(size_t)node * 64 + lane] = f2bf(acc0 + acc1);
}

// ---------------------------------------------------------------------------
// MFMA node transform: out = leaky([agg | root] @ Bt^T + b)
// Block = 128 rows x 64 cols; wave = 32 rows (2 m-strips) x 4 n-tiles.
// A/B fragments loaded directly from global (no LDS). 16x16x32 bf16 MFMA.
// ---------------------------------------------------------------------------
template <bool POOL>
__global__ __launch_bounds__(256)
void mfma_transform(const unsigned short* __restrict__ aggB,
                    const unsigned short* __restrict__ rootB,
                    const unsigned short* __restrict__ Bt,
                    const float* __restrict__ bias,
                    unsigned short* __restrict__ xoutB,
                    const int* __restrict__ batch,
                    float* __restrict__ pooled, int N) {
    const int wave = threadIdx.x >> 6;
    const int lane = threadIdx.x & 63;
    const int quad = lane >> 4;
    const int l16  = lane & 15;
    const int m0   = blockIdx.x * 128 + wave * 32;

    short8 bf[4][4];
#pragma unroll
    for (int t = 0; t < 4; ++t)
#pragma unroll
        for (int k = 0; k < 4; ++k)
            bf[t][k] = *(const short8*)(Bt + (t * 16 + l16) * 128 + k * 32 + quad * 8);

    f32x4 acc[2][4];
#pragma unroll
    for (int s = 0; s < 2; ++s)
#pragma unroll
        for (int t = 0; t < 4; ++t)
            acc[s][t] = (f32x4){0.f, 0.f, 0.f, 0.f};

#pragma unroll
    for (int s = 0; s < 2; ++s) {
        int row = m0 + s * 16 + l16;
        int rowc = row < N ? row : N - 1;   // clamp; garbage rows masked at store
        const unsigned short* arow = aggB  + (size_t)rowc * 64;
        const unsigned short* xrow = rootB + (size_t)rowc * 64;
        short8 af[4];
        af[0] = *(const short8*)(arow + quad * 8);
        af[1] = *(const short8*)(arow + 32 + quad * 8);
        af[2] = *(const short8*)(xrow + quad * 8);
        af[3] = *(const short8*)(xrow + 32 + quad * 8);
#pragma unroll
        for (int t = 0; t < 4; ++t)
#pragma unroll
            for (int k = 0; k < 4; ++k)
                acc[s][t] = __builtin_amdgcn_mfma_f32_16x16x32_bf16(af[k], bf[t][k],
                                                                    acc[s][t], 0, 0, 0);
    }

#pragma unroll
    for (int s = 0; s < 2; ++s) {
#pragma unroll
        for (int t = 0; t < 4; ++t) {
            const int col = t * 16 + l16;
            const float b = bias[col];
            const int rowbase = m0 + s * 16 + quad * 4;
            if (!POOL) {
#pragma unroll
                for (int r = 0; r < 4; ++r) {
                    int row = rowbase + r;
                    if (row < N) {
                        float v = acc[s][t][r] + b;
                        v = (v > 0.0f) ? v : LEAKY_SLOPE * v;
                        xoutB[(size_t)row * 64 + col] = f2bf(v);
                    }
                }
            } else {
                float v[4]; int g[4]; int nv = 0;
#pragma unroll
                for (int r = 0; r < 4; ++r) {
                    int row = rowbase + r;
                    if (row < N) {
                        float a = acc[s][t][r] + b;
                        a = (a > 0.0f) ? a : LEAKY_SLOPE * a;
                        v[nv] = a;
                        g[nv] = batch[row];
                        ++nv;
                    }
                }
                if (nv == 4 && g[0] == g[3]) {
                    atomicAdd(&pooled[g[0] * 64 + col], v[0] + v[1] + v[2] + v[3]);
                } else {
                    for (int r = 0; r < nv; ++r)
                        atomicAdd(&pooled[g[r] * 64 + col], v[r]);
                }
            }
        }
    }
}

// ---------------------------------------------------------------------------
// Final: cnt[g] via binary search on sorted batch (no atomics);
// out[g,:] = (pooled[g,:]/max(cnt,1)) @ Wl[64,8] + bl
// ---------------------------------------------------------------------------
__global__ __launch_bounds__(64)
void final_kernel(const float* __restrict__ pooled, const int* __restrict__ batch,
                  int N, const float* __restrict__ Wl, const float* __restrict__ bl,
                  float* __restrict__ out) {
    const int g = blockIdx.x;
    const int j = threadIdx.x;
    __shared__ float sp[64];
    __shared__ int scnt;
    if (j == 0) {
        int lo = 0, hi = N;
        while (lo < hi) { int mid = (lo + hi) >> 1; if (batch[mid] < g) lo = mid + 1; else hi = mid; }
        const int start = lo;
        hi = N;
        while (lo < hi) { int mid = (lo + hi) >> 1; if (batch[mid] < g + 1) lo = mid + 1; else hi = mid; }
        scnt = lo - start;
    }
    __syncthreads();
    const float c = fmaxf((float)scnt, 1.0f);
    sp[j] = pooled[g * 64 + j] / c;
    __syncthreads();
    if (j < 8) {
        float acc = bl[j];
#pragma unroll
        for (int k = 0; k < 64; ++k) acc += sp[k] * Wl[k * 8 + j];
        out[g * 8 + j] = acc;
    }
}

extern "C" void kernel_launch(void* const* d_in, const int* in_sizes, int n_in,
                              void* d_out, int out_size, void* d_ws, size_t ws_size,
                              hipStream_t stream) {
    const float* x      = (const float*)d_in[0];
    const int*   ei     = (const int*)  d_in[1];  // [2,E]: src then dst
    const float* w      = (const float*)d_in[2];
    const int*   batch  = (const int*)  d_in[3];
    const float* W1root = (const float*)d_in[4];
    const float* W1rel  = (const float*)d_in[5];
    const float* b1     = (const float*)d_in[6];
    const float* W2root = (const float*)d_in[7];
    const float* W2rel  = (const float*)d_in[8];
    const float* b2     = (const float*)d_in[9];
    const float* Wl     = (const float*)d_in[10];
    const float* bl     = (const float*)d_in[11];
    float* out = (float*)d_out;

    const int E = in_sizes[2];      // 1,250,000
    const int N = in_sizes[3];      // 100,000
    const int* src = ei;
    const int* dst = ei + E;

    // Workspace layout (16B-aligned chunks first)
    unsigned short* xB   = (unsigned short*)d_ws;          // [N*64] bf16
    unsigned short* aggB = xB   + (size_t)N * 64;          // [N*64]
    unsigned short* x1B  = aggB + (size_t)N * 64;          // [N*64]
    int2*  edata    = (int2*)(x1B + (size_t)N * 64);       // [E]
    unsigned short* Bt1 = (unsigned short*)(edata + E);    // [64*128]
    unsigned short* Bt2 = Bt1 + 64 * 128;                  // [64*128]
    int*   rowStart = (int*)(Bt2 + 64 * 128);              // [N+1]
    int*   cursor   = rowStart + (N + 1);                  // [N]
    int*   deg      = cursor + N;                          // [N]
    int*   blockSums= deg + N;                             // [128]
    float* pooled   = (float*)(blockSums + 128);           // [512*64]

    const int edgeBlocks = (E + 255) / 256;
    const int scanBlocks = (N + SCAN_TILE - 1) / SCAN_TILE;

    // ---- CSR build + prep ----
    hipMemsetAsync(deg, 0, (size_t)N * sizeof(int), stream);
    hipMemsetAsync(pooled, 0, (size_t)NUM_GRAPHS * 64 * sizeof(float), stream);
    hist_kernel<<<edgeBlocks, 256, 0, stream>>>(dst, deg, E);
    prep_x_kernel<<<(N * 32 + 255) / 256, 256, 0, stream>>>(x, xB, N * 32);
    prep_B_kernel<<<64, 256, 0, stream>>>(W1rel, W1root, W2rel, W2root, Bt1, Bt2);
    scan1_kernel<<<scanBlocks, SCAN_TILE, 0, stream>>>(deg, blockSums, N);
    scan2_kernel<<<1, 64, 0, stream>>>(blockSums, scanBlocks);
    scan3_kernel<<<(N + 255) / 256, 256, 0, stream>>>(deg, blockSums, rowStart, cursor, N, E);
    fill_kernel<<<edgeBlocks, 256, 0, stream>>>(src, dst, w, cursor, edata, E);

    const int tBlocks = (N + 127) / 128;
    // ---- Layer 1 ----
    gather_kernel<<<(N + 3) / 4, 256, 0, stream>>>(xB, rowStart, edata, aggB, N);
    mfma_transform<false><<<tBlocks, 256, 0, stream>>>(aggB, xB, Bt1, b1, x1B,
                                                       nullptr, nullptr, N);
    // ---- Layer 2 ----
    gather_kernel<<<(N + 3) / 4, 256, 0, stream>>>(x1B, rowStart, edata, aggB, N);
    mfma_transform<true><<<tBlocks, 256, 0, stream>>>(aggB, x1B, Bt2, b2, nullptr,
                                                      batch, pooled, N);
    // ---- Pool + classify ----
    final_kernel<<<NUM_GRAPHS, 64, 0, stream>>>(pooled, batch, N, Wl, bl, out);
}

// Round 5
// 341.799 us; speedup vs baseline: 2.6695x; 1.2824x over previous
//
#include <hip/hip_runtime.h>

#define LEAKY_SLOPE 0.01f
#define NUM_GRAPHS 512
#define SCAN_TILE 1024

typedef __attribute__((ext_vector_type(8))) short short8;   // 8 x bf16 (4 VGPRs)
typedef __attribute__((ext_vector_type(4))) float f32x4;    // MFMA C/D

// fp32 -> bf16 round-to-nearest-even
static __device__ __forceinline__ unsigned short f2bf(float f) {
    unsigned u = __float_as_uint(f);
    u += 0x7FFFu + ((u >> 16) & 1u);
    return (unsigned short)(u >> 16);
}
static __device__ __forceinline__ float bf2f(unsigned short h) {
    return __uint_as_float(((unsigned)h) << 16);
}

// ---------------------------------------------------------------------------
// CSR build step 1: degree histogram + per-edge within-node rank.
// rank removes the atomic->store dependency from fill (R4: fill was bound by
// the atomicAdd(cursor) round-trip, 86 us).
// ---------------------------------------------------------------------------
__global__ __launch_bounds__(256)
void hist_kernel(const int* __restrict__ dst, int* __restrict__ deg,
                 unsigned short* __restrict__ rank, int E) {
    int e = blockIdx.x * blockDim.x + threadIdx.x;
    if (e < E) rank[e] = (unsigned short)atomicAdd(&deg[dst[e]], 1);
}

__global__ __launch_bounds__(SCAN_TILE)
void scan1_kernel(int* __restrict__ deg, int* __restrict__ blockSums, int N) {
    __shared__ int buf[2][SCAN_TILE];
    const int i = blockIdx.x * SCAN_TILE + threadIdx.x;
    const int v = (i < N) ? deg[i] : 0;
    int pp = 0;
    buf[0][threadIdx.x] = v;
    __syncthreads();
    for (int off = 1; off < SCAN_TILE; off <<= 1) {
        int val = buf[pp][threadIdx.x];
        if ((int)threadIdx.x >= off) val += buf[pp][threadIdx.x - off];
        buf[pp ^ 1][threadIdx.x] = val;
        pp ^= 1;
        __syncthreads();
    }
    const int inc = buf[pp][threadIdx.x];
    if (i < N) deg[i] = inc - v;  // exclusive, in place
    if (threadIdx.x == SCAN_TILE - 1) blockSums[blockIdx.x] = inc;
}

__global__ void scan2_kernel(int* __restrict__ blockSums, int B) {
    if (threadIdx.x == 0 && blockIdx.x == 0) {
        int run = 0;
        for (int b = 0; b < B; ++b) { int t = blockSums[b]; blockSums[b] = run; run += t; }
    }
}

__global__ __launch_bounds__(256)
void scan3_kernel(const int* __restrict__ excl, const int* __restrict__ blockSums,
                  int* __restrict__ rowStart, int N, int E) {
    int i = blockIdx.x * blockDim.x + threadIdx.x;
    if (i < N) rowStart[i] = excl[i] + blockSums[i >> 10];
    if (i == 0) rowStart[N] = E;
}

// ---------------------------------------------------------------------------
// CSR fill, no atomics: pos = rowStart[dst] + rank. Scattered store is
// fire-and-forget.
// ---------------------------------------------------------------------------
__global__ __launch_bounds__(256)
void fill_kernel(const int* __restrict__ src, const int* __restrict__ dst,
                 const float* __restrict__ w, const int* __restrict__ rowStart,
                 const unsigned short* __restrict__ rank,
                 int2* __restrict__ edata, int E) {
    int e = blockIdx.x * blockDim.x + threadIdx.x;
    if (e < E) {
        int pos = rowStart[dst[e]] + (int)rank[e];
        edata[pos] = make_int2(src[e], __float_as_int(w[e]));
    }
}

// ---------------------------------------------------------------------------
// Prep: x fp32 -> bf16
// ---------------------------------------------------------------------------
__global__ __launch_bounds__(256)
void prep_x_kernel(const float* __restrict__ x, unsigned short* __restrict__ xB, int n2) {
    int i = blockIdx.x * blockDim.x + threadIdx.x;   // one thread per 2 elements
    if (i < n2) {
        float2 f = ((const float2*)x)[i];
        ushort2 o = make_ushort2(f2bf(f.x), f2bf(f.y));
        ((ushort2*)xB)[i] = o;
    }
}

// Prep both layers' Bt[n][k] (64x128 bf16 each): k<64 -> Wrel[k][n], else Wroot
__global__ __launch_bounds__(256)
void prep_B_kernel(const float* __restrict__ W1rel, const float* __restrict__ W1root,
                   const float* __restrict__ W2rel, const float* __restrict__ W2root,
                   unsigned short* __restrict__ Bt1, unsigned short* __restrict__ Bt2) {
    int idx = blockIdx.x * blockDim.x + threadIdx.x;  // 2 * 64*128 = 16384
    if (idx < 2 * 64 * 128) {
        int which = idx >> 13;
        int j = idx & 8191;
        int n = j >> 7, k = j & 127;
        const float* Wr = which ? W2rel : W1rel;
        const float* Wo = which ? W2root : W1root;
        float v = (k < 64) ? Wr[k * 64 + n] : Wo[(k - 64) * 64 + n];
        (which ? Bt2 : Bt1)[j] = f2bf(v);
    }
}

// ---------------------------------------------------------------------------
// Gather aggregation, 4-edge-parallel: one wave per node; lane L covers
// features (L&15)*4..+3 of edge j+(L>>4). One 8B load per lane pulls 4 rows
// (512 B) per instruction; x2 unroll = 8 edges in flight. Final shfl_xor(16,32)
// combines the 4 edge groups; group-0 lanes store the packed bf16 row.
// ---------------------------------------------------------------------------
__global__ __launch_bounds__(256)
void gather_kernel(const unsigned short* __restrict__ xB, const int* __restrict__ rowStart,
                   const int2* __restrict__ edata, unsigned short* __restrict__ aggB, int N) {
    const int node = blockIdx.x * 4 + (threadIdx.x >> 6);
    if (node >= N) return;
    const int lane = threadIdx.x & 63;
    const int grp  = lane >> 4;          // 0..3: edge slot within quad
    const int f4   = (lane & 15) * 4;    // feature base (4 features/lane)
    const int s = rowStart[node];
    const int e = rowStart[node + 1];

    float a0 = 0.f, a1 = 0.f, a2 = 0.f, a3 = 0.f;
    for (int j = s; j < e; j += 8) {
        const int eA = j + grp;
        const int eB = j + 4 + grp;
        const bool vA = eA < e;
        const bool vB = eB < e;
        int2 edA = edata[vA ? eA : s];
        int2 edB = edata[vB ? eB : s];
        const float wA = vA ? __int_as_float(edA.y) : 0.0f;
        const float wB = vB ? __int_as_float(edB.y) : 0.0f;
        ushort4 rA = *(const ushort4*)(xB + (size_t)edA.x * 64 + f4);
        ushort4 rB = *(const ushort4*)(xB + (size_t)edB.x * 64 + f4);
        a0 += bf2f(rA.x) * wA;  a1 += bf2f(rA.y) * wA;
        a2 += bf2f(rA.z) * wA;  a3 += bf2f(rA.w) * wA;
        a0 += bf2f(rB.x) * wB;  a1 += bf2f(rB.y) * wB;
        a2 += bf2f(rB.z) * wB;  a3 += bf2f(rB.w) * wB;
    }
    // combine the 4 edge groups (lanes differing in bits 4,5)
    a0 += __shfl_xor(a0, 16, 64);  a1 += __shfl_xor(a1, 16, 64);
    a2 += __shfl_xor(a2, 16, 64);  a3 += __shfl_xor(a3, 16, 64);
    a0 += __shfl_xor(a0, 32, 64);  a1 += __shfl_xor(a1, 32, 64);
    a2 += __shfl_xor(a2, 32, 64);  a3 += __shfl_xor(a3, 32, 64);
    if (grp == 0) {
        ushort4 o = make_ushort4(f2bf(a0), f2bf(a1), f2bf(a2), f2bf(a3));
        *(ushort4*)(aggB + (size_t)node * 64 + f4) = o;
    }
}

// ---------------------------------------------------------------------------
// MFMA node transform: out = leaky([agg | root] @ Bt^T + b)
// Block = 128 rows x 64 cols; wave = 32 rows (2 m-strips) x 4 n-tiles.
// A/B fragments loaded directly from global (no LDS). 16x16x32 bf16 MFMA.
// ---------------------------------------------------------------------------
template <bool POOL>
__global__ __launch_bounds__(256)
void mfma_transform(const unsigned short* __restrict__ aggB,
                    const unsigned short* __restrict__ rootB,
                    const unsigned short* __restrict__ Bt,
                    const float* __restrict__ bias,
                    unsigned short* __restrict__ xoutB,
                    const int* __restrict__ batch,
                    float* __restrict__ pooled, int N) {
    const int wave = threadIdx.x >> 6;
    const int lane = threadIdx.x & 63;
    const int quad = lane >> 4;
    const int l16  = lane & 15;
    const int m0   = blockIdx.x * 128 + wave * 32;

    short8 bf[4][4];
#pragma unroll
    for (int t = 0; t < 4; ++t)
#pragma unroll
        for (int k = 0; k < 4; ++k)
            bf[t][k] = *(const short8*)(Bt + (t * 16 + l16) * 128 + k * 32 + quad * 8);

    f32x4 acc[2][4];
#pragma unroll
    for (int s = 0; s < 2; ++s)
#pragma unroll
        for (int t = 0; t < 4; ++t)
            acc[s][t] = (f32x4){0.f, 0.f, 0.f, 0.f};

#pragma unroll
    for (int s = 0; s < 2; ++s) {
        int row = m0 + s * 16 + l16;
        int rowc = row < N ? row : N - 1;   // clamp; garbage rows masked at store
        const unsigned short* arow = aggB  + (size_t)rowc * 64;
        const unsigned short* xrow = rootB + (size_t)rowc * 64;
        short8 af[4];
        af[0] = *(const short8*)(arow + quad * 8);
        af[1] = *(const short8*)(arow + 32 + quad * 8);
        af[2] = *(const short8*)(xrow + quad * 8);
        af[3] = *(const short8*)(xrow + 32 + quad * 8);
#pragma unroll
        for (int t = 0; t < 4; ++t)
#pragma unroll
            for (int k = 0; k < 4; ++k)
                acc[s][t] = __builtin_amdgcn_mfma_f32_16x16x32_bf16(af[k], bf[t][k],
                                                                    acc[s][t], 0, 0, 0);
    }

#pragma unroll
    for (int s = 0; s < 2; ++s) {
#pragma unroll
        for (int t = 0; t < 4; ++t) {
            const int col = t * 16 + l16;
            const float b = bias[col];
            const int rowbase = m0 + s * 16 + quad * 4;
            if (!POOL) {
#pragma unroll
                for (int r = 0; r < 4; ++r) {
                    int row = rowbase + r;
                    if (row < N) {
                        float v = acc[s][t][r] + b;
                        v = (v > 0.0f) ? v : LEAKY_SLOPE * v;
                        xoutB[(size_t)row * 64 + col] = f2bf(v);
                    }
                }
            } else {
                float v[4]; int g[4]; int nv = 0;
#pragma unroll
                for (int r = 0; r < 4; ++r) {
                    int row = rowbase + r;
                    if (row < N) {
                        float a = acc[s][t][r] + b;
                        a = (a > 0.0f) ? a : LEAKY_SLOPE * a;
                        v[nv] = a;
                        g[nv] = batch[row];
                        ++nv;
                    }
                }
                if (nv == 4 && g[0] == g[3]) {
                    atomicAdd(&pooled[g[0] * 64 + col], v[0] + v[1] + v[2] + v[3]);
                } else {
                    for (int r = 0; r < nv; ++r)
                        atomicAdd(&pooled[g[r] * 64 + col], v[r]);
                }
            }
        }
    }
}

// ---------------------------------------------------------------------------
// Final: cnt[g] via binary search on sorted batch (no atomics);
// out[g,:] = (pooled[g,:]/max(cnt,1)) @ Wl[64,8] + bl
// ---------------------------------------------------------------------------
__global__ __launch_bounds__(64)
void final_kernel(const float* __restrict__ pooled, const int* __restrict__ batch,
                  int N, const float* __restrict__ Wl, const float* __restrict__ bl,
                  float* __restrict__ out) {
    const int g = blockIdx.x;
    const int j = threadIdx.x;
    __shared__ float sp[64];
    __shared__ int scnt;
    if (j == 0) {
        int lo = 0, hi = N;
        while (lo < hi) { int mid = (lo + hi) >> 1; if (batch[mid] < g) lo = mid + 1; else hi = mid; }
        const int start = lo;
        hi = N;
        while (lo < hi) { int mid = (lo + hi) >> 1; if (batch[mid] < g + 1) lo = mid + 1; else hi = mid; }
        scnt = lo - start;
    }
    __syncthreads();
    const float c = fmaxf((float)scnt, 1.0f);
    sp[j] = pooled[g * 64 + j] / c;
    __syncthreads();
    if (j < 8) {
        float acc = bl[j];
#pragma unroll
        for (int k = 0; k < 64; ++k) acc += sp[k] * Wl[k * 8 + j];
        out[g * 8 + j] = acc;
    }
}

extern "C" void kernel_launch(void* const* d_in, const int* in_sizes, int n_in,
                              void* d_out, int out_size, void* d_ws, size_t ws_size,
                              hipStream_t stream) {
    const float* x      = (const float*)d_in[0];
    const int*   ei     = (const int*)  d_in[1];  // [2,E]: src then dst
    const float* w      = (const float*)d_in[2];
    const int*   batch  = (const int*)  d_in[3];
    const float* W1root = (const float*)d_in[4];
    const float* W1rel  = (const float*)d_in[5];
    const float* b1     = (const float*)d_in[6];
    const float* W2root = (const float*)d_in[7];
    const float* W2rel  = (const float*)d_in[8];
    const float* b2     = (const float*)d_in[9];
    const float* Wl     = (const float*)d_in[10];
    const float* bl     = (const float*)d_in[11];
    float* out = (float*)d_out;

    const int E = in_sizes[2];      // 1,250,000
    const int N = in_sizes[3];      // 100,000
    const int* src = ei;
    const int* dst = ei + E;

    // Workspace layout (16B-aligned chunks first)
    unsigned short* xB   = (unsigned short*)d_ws;          // [N*64] bf16
    unsigned short* aggB = xB   + (size_t)N * 64;          // [N*64]
    unsigned short* x1B  = aggB + (size_t)N * 64;          // [N*64]
    int2*  edata    = (int2*)(x1B + (size_t)N * 64);       // [E]
    unsigned short* Bt1 = (unsigned short*)(edata + E);    // [64*128]
    unsigned short* Bt2 = Bt1 + 64 * 128;                  // [64*128]
    unsigned short* rank = Bt2 + 64 * 128;                 // [E] uint16
    int*   rowStart = (int*)(rank + E + (E & 1));          // [N+1]
    int*   deg      = rowStart + (N + 1);                  // [N]
    int*   blockSums= deg + N;                             // [128]
    float* pooled   = (float*)(blockSums + 128);           // [512*64]

    const int edgeBlocks = (E + 255) / 256;
    const int scanBlocks = (N + SCAN_TILE - 1) / SCAN_TILE;

    // ---- CSR build + prep ----
    hipMemsetAsync(deg, 0, (size_t)N * sizeof(int), stream);
    hipMemsetAsync(pooled, 0, (size_t)NUM_GRAPHS * 64 * sizeof(float), stream);
    hist_kernel<<<edgeBlocks, 256, 0, stream>>>(dst, deg, rank, E);
    prep_x_kernel<<<(N * 32 + 255) / 256, 256, 0, stream>>>(x, xB, N * 32);
    prep_B_kernel<<<64, 256, 0, stream>>>(W1rel, W1root, W2rel, W2root, Bt1, Bt2);
    scan1_kernel<<<scanBlocks, SCAN_TILE, 0, stream>>>(deg, blockSums, N);
    scan2_kernel<<<1, 64, 0, stream>>>(blockSums, scanBlocks);
    scan3_kernel<<<(N + 255) / 256, 256, 0, stream>>>(deg, blockSums, rowStart, N, E);
    fill_kernel<<<edgeBlocks, 256, 0, stream>>>(src, dst, w, rowStart, rank, edata, E);

    const int tBlocks = (N + 127) / 128;
    // ---- Layer 1 ----
    gather_kernel<<<(N + 3) / 4, 256, 0, stream>>>(xB, rowStart, edata, aggB, N);
    mfma_transform<false><<<tBlocks, 256, 0, stream>>>(aggB, xB, Bt1, b1, x1B,
                                                       nullptr, nullptr, N);
    // ---- Layer 2 ----
    gather_kernel<<<(N + 3) / 4, 256, 0, stream>>>(x1B, rowStart, edata, aggB, N);
    mfma_transform<true><<<tBlocks, 256, 0, stream>>>(aggB, x1B, Bt2, b2, nullptr,
                                                      batch, pooled, N);
    // ---- Pool + classify ----
    final_kernel<<<NUM_GRAPHS, 64, 0, stream>>>(pooled, batch, N, Wl, bl, out);
}

// Round 6
// 298.708 us; speedup vs baseline: 3.0546x; 1.1443x over previous
//
#include <hip/hip_runtime.h>

#define LEAKY_SLOPE 0.01f
#define NUM_GRAPHS 512
#define TILE 4096            // edges per partition block
#define NB_MAX 512           // max dst buckets (N <= 131072)

typedef __attribute__((ext_vector_type(8))) short short8;   // 8 x bf16 (4 VGPRs)
typedef __attribute__((ext_vector_type(4))) float f32x4;    // MFMA C/D

// fp32 -> bf16 round-to-nearest-even
static __device__ __forceinline__ unsigned short f2bf(float f) {
    unsigned u = __float_as_uint(f);
    u += 0x7FFFu + ((u >> 16) & 1u);
    return (unsigned short)(u >> 16);
}
static __device__ __forceinline__ float bf2f(unsigned short h) {
    return __uint_as_float(((unsigned)h) << 16);
}

static __device__ __forceinline__ int wave_incl_scan(int v, int lane) {
#pragma unroll
    for (int off = 1; off < 64; off <<= 1) {
        int t = __shfl_up(v, off, 64);
        if (lane >= off) v += t;
    }
    return v;
}

// ---------------------------------------------------------------------------
// p1a: coarse histogram of dst>>8 into NB buckets. All per-edge atomics in LDS;
// only NB global atomics per block.
// ---------------------------------------------------------------------------
__global__ __launch_bounds__(256)
void p1a_hist(const int* __restrict__ dst, int* __restrict__ bucketCnt, int E, int NB) {
    __shared__ int h[NB_MAX];
    for (int t = threadIdx.x; t < NB_MAX; t += 256) h[t] = 0;
    __syncthreads();
    const int base = blockIdx.x * TILE;
#pragma unroll
    for (int i = 0; i < TILE / 256; ++i) {
        int e = base + i * 256 + threadIdx.x;
        if (e < E) atomicAdd(&h[dst[e] >> 8], 1);
    }
    __syncthreads();
    for (int t = threadIdx.x; t < NB; t += 256)
        if (h[t]) atomicAdd(&bucketCnt[t], h[t]);
}

// ---------------------------------------------------------------------------
// bscan: exclusive scan of bucket counts -> bucketBase & global cursors;
// also sets rowStart[N] = E.  One block, 512 threads.
// ---------------------------------------------------------------------------
__global__ __launch_bounds__(512)
void bscan_kernel(const int* __restrict__ bucketCnt, int* __restrict__ bucketBase,
                  int* __restrict__ cursor, int* __restrict__ rowStart,
                  int N, int E, int NB) {
    __shared__ int ws[8];
    const int t = threadIdx.x, lane = t & 63, wid = t >> 6;
    int v = (t < NB) ? bucketCnt[t] : 0;
    int s = wave_incl_scan(v, lane);
    if (lane == 63) ws[wid] = s;
    __syncthreads();
    int add = 0;
    for (int i = 0; i < wid; ++i) add += ws[i];
    if (t < NB) {
        int excl = s + add - v;
        bucketBase[t] = excl;
        cursor[t] = excl;
    }
    if (t == 0) rowStart[N] = E;
}

// ---------------------------------------------------------------------------
// p1b: radix partition by dst>>8. Tile -> LDS hist -> LDS scan -> LDS reorder
// -> per-(block,bucket) global reservation -> coalesced run writes to tmp.
// Payload packed: .x = src | (dst&255)<<20, .y = w bits.
// ---------------------------------------------------------------------------
__global__ __launch_bounds__(256)
void p1b_partition(const int* __restrict__ src, const int* __restrict__ dst,
                   const float* __restrict__ w, int* __restrict__ cursor,
                   int2* __restrict__ tmp, int E, int NB) {
    __shared__ int h[NB_MAX];
    __shared__ int cur[NB_MAX];
    __shared__ int lstart[NB_MAX];
    __shared__ int gbase[NB_MAX];
    __shared__ int ws[4];
    __shared__ int2 pay[TILE];
    __shared__ unsigned short bk[TILE];

    for (int t = threadIdx.x; t < NB_MAX; t += 256) h[t] = 0;
    __syncthreads();

    const int base = blockIdx.x * TILE;
    int   myb[TILE / 256];
    int   myp[TILE / 256];
    float myw[TILE / 256];
#pragma unroll
    for (int i = 0; i < TILE / 256; ++i) {
        int e = base + i * 256 + threadIdx.x;
        if (e < E) {
            int d = dst[e];
            myb[i] = d >> 8;
            myp[i] = src[e] | ((d & 255) << 20);
            myw[i] = w[e];
            atomicAdd(&h[myb[i]], 1);
        } else {
            myb[i] = -1;
        }
    }
    __syncthreads();

    // exclusive scan of h[0..511] (pairwise: thread t owns 2t, 2t+1)
    {
        const int t = threadIdx.x, lane = t & 63, wid = t >> 6;
        int a = h[2 * t], b = h[2 * t + 1];
        int s = wave_incl_scan(a + b, lane);
        if (lane == 63) ws[wid] = s;
        __syncthreads();
        int add = 0;
        for (int i = 0; i < wid; ++i) add += ws[i];
        int excl = s + add - (a + b);
        lstart[2 * t] = excl;
        lstart[2 * t + 1] = excl + a;
        cur[2 * t] = excl;
        cur[2 * t + 1] = excl + a;
    }
    __syncthreads();

    // reorder into LDS by bucket
#pragma unroll
    for (int i = 0; i < TILE / 256; ++i) {
        if (myb[i] >= 0) {
            int p = atomicAdd(&cur[myb[i]], 1);
            pay[p] = make_int2(myp[i], __float_as_int(myw[i]));
            bk[p] = (unsigned short)myb[i];
        }
    }
    __syncthreads();

    // reserve global space: one atomic per non-empty bucket
    for (int t = threadIdx.x; t < NB; t += 256) {
        int c = h[t];
        if (c) gbase[t] = atomicAdd(&cursor[t], c);
    }
    __syncthreads();

    // coalesced-run writes
    const int total = min(TILE, E - base);
    for (int s2 = threadIdx.x; s2 < total; s2 += 256) {
        int b2 = bk[s2];
        tmp[gbase[b2] + s2 - lstart[b2]] = pay[s2];
    }
}

// ---------------------------------------------------------------------------
// p2: one block per bucket. LDS hist of 256 local dst values -> scan ->
// rowStart + final dst-sorted edata (src, w fp32).
// ---------------------------------------------------------------------------
__global__ __launch_bounds__(256)
void p2_build(const int2* __restrict__ tmp, const int* __restrict__ bucketBase,
              int* __restrict__ rowStart, int2* __restrict__ edata,
              int N, int E, int NB) {
    const int b = blockIdx.x;
    const int s = bucketBase[b];
    const int e2 = (b + 1 < NB) ? bucketBase[b + 1] : E;
    __shared__ int h[256];
    __shared__ int cur[256];
    __shared__ int ws[4];
    h[threadIdx.x] = 0;
    __syncthreads();
    for (int j = s + threadIdx.x; j < e2; j += 256) {
        int dl = (tmp[j].x >> 20) & 255;
        atomicAdd(&h[dl], 1);
    }
    __syncthreads();
    const int t = threadIdx.x, lane = t & 63, wid = t >> 6;
    int v = h[t];
    int sc = wave_incl_scan(v, lane);
    if (lane == 63) ws[wid] = sc;
    __syncthreads();
    int add = 0;
    for (int i = 0; i < wid; ++i) add += ws[i];
    int excl = sc + add - v;
    const int node = b * 256 + t;
    if (node < N) rowStart[node] = s + excl;
    cur[t] = excl;
    __syncthreads();
    for (int j = s + threadIdx.x; j < e2; j += 256) {
        int2 v2 = tmp[j];
        int dl = (v2.x >> 20) & 255;
        int p = atomicAdd(&cur[dl], 1);
        edata[s + p] = make_int2(v2.x & 0x1FFFF, v2.y);
    }
}

// ---------------------------------------------------------------------------
// Prep: x fp32 -> bf16
// ---------------------------------------------------------------------------
__global__ __launch_bounds__(256)
void prep_x_kernel(const float* __restrict__ x, unsigned short* __restrict__ xB, int n2) {
    int i = blockIdx.x * blockDim.x + threadIdx.x;
    if (i < n2) {
        float2 f = ((const float2*)x)[i];
        ushort2 o = make_ushort2(f2bf(f.x), f2bf(f.y));
        ((ushort2*)xB)[i] = o;
    }
}

// Prep both layers' Bt[n][k] (64x128 bf16 each): k<64 -> Wrel[k][n], else Wroot
__global__ __launch_bounds__(256)
void prep_B_kernel(const float* __restrict__ W1rel, const float* __restrict__ W1root,
                   const float* __restrict__ W2rel, const float* __restrict__ W2root,
                   unsigned short* __restrict__ Bt1, unsigned short* __restrict__ Bt2) {
    int idx = blockIdx.x * blockDim.x + threadIdx.x;
    if (idx < 2 * 64 * 128) {
        int which = idx >> 13;
        int j = idx & 8191;
        int n = j >> 7, k = j & 127;
        const float* Wr = which ? W2rel : W1rel;
        const float* Wo = which ? W2root : W1root;
        float v = (k < 64) ? Wr[k * 64 + n] : Wo[(k - 64) * 64 + n];
        (which ? Bt2 : Bt1)[j] = f2bf(v);
    }
}

// ---------------------------------------------------------------------------
// Gather aggregation, 4-edge-parallel (unchanged from R5)
// ---------------------------------------------------------------------------
__global__ __launch_bounds__(256)
void gather_kernel(const unsigned short* __restrict__ xB, const int* __restrict__ rowStart,
                   const int2* __restrict__ edata, unsigned short* __restrict__ aggB, int N) {
    const int node = blockIdx.x * 4 + (threadIdx.x >> 6);
    if (node >= N) return;
    const int lane = threadIdx.x & 63;
    const int grp  = lane >> 4;
    const int f4   = (lane & 15) * 4;
    const int s = rowStart[node];
    const int e = rowStart[node + 1];

    float a0 = 0.f, a1 = 0.f, a2 = 0.f, a3 = 0.f;
    for (int j = s; j < e; j += 8) {
        const int eA = j + grp;
        const int eB = j + 4 + grp;
        const bool vA = eA < e;
        const bool vB = eB < e;
        int2 edA = edata[vA ? eA : s];
        int2 edB = edata[vB ? eB : s];
        const float wA = vA ? __int_as_float(edA.y) : 0.0f;
        const float wB = vB ? __int_as_float(edB.y) : 0.0f;
        ushort4 rA = *(const ushort4*)(xB + (size_t)edA.x * 64 + f4);
        ushort4 rB = *(const ushort4*)(xB + (size_t)edB.x * 64 + f4);
        a0 += bf2f(rA.x) * wA;  a1 += bf2f(rA.y) * wA;
        a2 += bf2f(rA.z) * wA;  a3 += bf2f(rA.w) * wA;
        a0 += bf2f(rB.x) * wB;  a1 += bf2f(rB.y) * wB;
        a2 += bf2f(rB.z) * wB;  a3 += bf2f(rB.w) * wB;
    }
    a0 += __shfl_xor(a0, 16, 64);  a1 += __shfl_xor(a1, 16, 64);
    a2 += __shfl_xor(a2, 16, 64);  a3 += __shfl_xor(a3, 16, 64);
    a0 += __shfl_xor(a0, 32, 64);  a1 += __shfl_xor(a1, 32, 64);
    a2 += __shfl_xor(a2, 32, 64);  a3 += __shfl_xor(a3, 32, 64);
    if (grp == 0) {
        ushort4 o = make_ushort4(f2bf(a0), f2bf(a1), f2bf(a2), f2bf(a3));
        *(ushort4*)(aggB + (size_t)node * 64 + f4) = o;
    }
}

// ---------------------------------------------------------------------------
// MFMA node transform (unchanged from R5)
// ---------------------------------------------------------------------------
template <bool POOL>
__global__ __launch_bounds__(256)
void mfma_transform(const unsigned short* __restrict__ aggB,
                    const unsigned short* __restrict__ rootB,
                    const unsigned short* __restrict__ Bt,
                    const float* __restrict__ bias,
                    unsigned short* __restrict__ xoutB,
                    const int* __restrict__ batch,
                    float* __restrict__ pooled, int N) {
    const int wave = threadIdx.x >> 6;
    const int lane = threadIdx.x & 63;
    const int quad = lane >> 4;
    const int l16  = lane & 15;
    const int m0   = blockIdx.x * 128 + wave * 32;

    short8 bf[4][4];
#pragma unroll
    for (int t = 0; t < 4; ++t)
#pragma unroll
        for (int k = 0; k < 4; ++k)
            bf[t][k] = *(const short8*)(Bt + (t * 16 + l16) * 128 + k * 32 + quad * 8);

    f32x4 acc[2][4];
#pragma unroll
    for (int s = 0; s < 2; ++s)
#pragma unroll
        for (int t = 0; t < 4; ++t)
            acc[s][t] = (f32x4){0.f, 0.f, 0.f, 0.f};

#pragma unroll
    for (int s = 0; s < 2; ++s) {
        int row = m0 + s * 16 + l16;
        int rowc = row < N ? row : N - 1;
        const unsigned short* arow = aggB  + (size_t)rowc * 64;
        const unsigned short* xrow = rootB + (size_t)rowc * 64;
        short8 af[4];
        af[0] = *(const short8*)(arow + quad * 8);
        af[1] = *(const short8*)(arow + 32 + quad * 8);
        af[2] = *(const short8*)(xrow + quad * 8);
        af[3] = *(const short8*)(xrow + 32 + quad * 8);
#pragma unroll
        for (int t = 0; t < 4; ++t)
#pragma unroll
            for (int k = 0; k < 4; ++k)
                acc[s][t] = __builtin_amdgcn_mfma_f32_16x16x32_bf16(af[k], bf[t][k],
                                                                    acc[s][t], 0, 0, 0);
    }

#pragma unroll
    for (int s = 0; s < 2; ++s) {
#pragma unroll
        for (int t = 0; t < 4; ++t) {
            const int col = t * 16 + l16;
            const float b = bias[col];
            const int rowbase = m0 + s * 16 + quad * 4;
            if (!POOL) {
#pragma unroll
                for (int r = 0; r < 4; ++r) {
                    int row = rowbase + r;
                    if (row < N) {
                        float v = acc[s][t][r] + b;
                        v = (v > 0.0f) ? v : LEAKY_SLOPE * v;
                        xoutB[(size_t)row * 64 + col] = f2bf(v);
                    }
                }
            } else {
                float v[4]; int g[4]; int nv = 0;
#pragma unroll
                for (int r = 0; r < 4; ++r) {
                    int row = rowbase + r;
                    if (row < N) {
                        float a = acc[s][t][r] + b;
                        a = (a > 0.0f) ? a : LEAKY_SLOPE * a;
                        v[nv] = a;
                        g[nv] = batch[row];
                        ++nv;
                    }
                }
                if (nv == 4 && g[0] == g[3]) {
                    atomicAdd(&pooled[g[0] * 64 + col], v[0] + v[1] + v[2] + v[3]);
                } else {
                    for (int r = 0; r < nv; ++r)
                        atomicAdd(&pooled[g[r] * 64 + col], v[r]);
                }
            }
        }
    }
}

// ---------------------------------------------------------------------------
// Final: cnt via binary search on sorted batch; tiny GEMM epilogue.
// ---------------------------------------------------------------------------
__global__ __launch_bounds__(64)
void final_kernel(const float* __restrict__ pooled, const int* __restrict__ batch,
                  int N, const float* __restrict__ Wl, const float* __restrict__ bl,
                  float* __restrict__ out) {
    const int g = blockIdx.x;
    const int j = threadIdx.x;
    __shared__ float sp[64];
    __shared__ int scnt;
    if (j == 0) {
        int lo = 0, hi = N;
        while (lo < hi) { int mid = (lo + hi) >> 1; if (batch[mid] < g) lo = mid + 1; else hi = mid; }
        const int start = lo;
        hi = N;
        while (lo < hi) { int mid = (lo + hi) >> 1; if (batch[mid] < g + 1) lo = mid + 1; else hi = mid; }
        scnt = lo - start;
    }
    __syncthreads();
    const float c = fmaxf((float)scnt, 1.0f);
    sp[j] = pooled[g * 64 + j] / c;
    __syncthreads();
    if (j < 8) {
        float acc = bl[j];
#pragma unroll
        for (int k = 0; k < 64; ++k) acc += sp[k] * Wl[k * 8 + j];
        out[g * 8 + j] = acc;
    }
}

extern "C" void kernel_launch(void* const* d_in, const int* in_sizes, int n_in,
                              void* d_out, int out_size, void* d_ws, size_t ws_size,
                              hipStream_t stream) {
    const float* x      = (const float*)d_in[0];
    const int*   ei     = (const int*)  d_in[1];  // [2,E]: src then dst
    const float* w      = (const float*)d_in[2];
    const int*   batch  = (const int*)  d_in[3];
    const float* W1root = (const float*)d_in[4];
    const float* W1rel  = (const float*)d_in[5];
    const float* b1     = (const float*)d_in[6];
    const float* W2root = (const float*)d_in[7];
    const float* W2rel  = (const float*)d_in[8];
    const float* b2     = (const float*)d_in[9];
    const float* Wl     = (const float*)d_in[10];
    const float* bl     = (const float*)d_in[11];
    float* out = (float*)d_out;

    const int E = in_sizes[2];      // 1,250,000
    const int N = in_sizes[3];      // 100,000
    const int* src = ei;
    const int* dst = ei + E;
    const int NB = (N + 255) / 256; // 391 dst buckets

    // Workspace layout (~59 MB)
    unsigned short* xB   = (unsigned short*)d_ws;          // [N*64] bf16
    unsigned short* aggB = xB   + (size_t)N * 64;          // [N*64]
    unsigned short* x1B  = aggB + (size_t)N * 64;          // [N*64]
    int2*  tmp      = (int2*)(x1B + (size_t)N * 64);       // [E] partitioned
    int2*  edata    = tmp + E;                             // [E] final CSR
    unsigned short* Bt1 = (unsigned short*)(edata + E);    // [64*128]
    unsigned short* Bt2 = Bt1 + 64 * 128;                  // [64*128]
    int*   rowStart = (int*)(Bt2 + 64 * 128);              // [N+1]
    int*   bucketCnt  = rowStart + (N + 1);                // [NB_MAX]
    int*   bucketBase = bucketCnt + NB_MAX;                // [NB_MAX]
    int*   cursor     = bucketBase + NB_MAX;               // [NB_MAX]
    float* pooled   = (float*)(cursor + NB_MAX);           // [512*64]

    const int PB = (E + TILE - 1) / TILE;   // 306 partition blocks

    // ---- CSR build (LDS-binned radix partition) + prep ----
    hipMemsetAsync(bucketCnt, 0, NB_MAX * sizeof(int), stream);
    hipMemsetAsync(pooled, 0, (size_t)NUM_GRAPHS * 64 * sizeof(float), stream);
    p1a_hist<<<PB, 256, 0, stream>>>(dst, bucketCnt, E, NB);
    prep_x_kernel<<<(N * 32 + 255) / 256, 256, 0, stream>>>(x, xB, N * 32);
    prep_B_kernel<<<64, 256, 0, stream>>>(W1rel, W1root, W2rel, W2root, Bt1, Bt2);
    bscan_kernel<<<1, 512, 0, stream>>>(bucketCnt, bucketBase, cursor, rowStart, N, E, NB);
    p1b_partition<<<PB, 256, 0, stream>>>(src, dst, w, cursor, tmp, E, NB);
    p2_build<<<NB, 256, 0, stream>>>(tmp, bucketBase, rowStart, edata, N, E, NB);

    const int tBlocks = (N + 127) / 128;
    // ---- Layer 1 ----
    gather_kernel<<<(N + 3) / 4, 256, 0, stream>>>(xB, rowStart, edata, aggB, N);
    mfma_transform<false><<<tBlocks, 256, 0, stream>>>(aggB, xB, Bt1, b1, x1B,
                                                       nullptr, nullptr, N);
    // ---- Layer 2 ----
    gather_kernel<<<(N + 3) / 4, 256, 0, stream>>>(x1B, rowStart, edata, aggB, N);
    mfma_transform<true><<<tBlocks, 256, 0, stream>>>(aggB, x1B, Bt2, b2, nullptr,
                                                      batch, pooled, N);
    // ---- Pool + classify ----
    final_kernel<<<NUM_GRAPHS, 64, 0, stream>>>(pooled, batch, N, Wl, bl, out);
}